// Round 7
// baseline (373.909 us; speedup 1.0000x reference)
//
#include <hip/hip_runtime.h>

#define NN 50000
#define EE 200000
#define RR 4
#define MCHUNK 12500
#define SLOTS 32          // ELL slots per (etype,dst); P(deg>=32 | Poisson(4)) ~ 1e-15

#define LDA 136   // LDS row stride (ushorts): 16B-aligned rows, frag reads <=2-way conflict (free)

typedef __attribute__((ext_vector_type(8))) short bf16x8;
typedef __attribute__((ext_vector_type(4))) float f32x4;

__device__ inline unsigned short f2bf(float x) {   // round-to-nearest-even
    unsigned int u = __float_as_uint(x);
    u += 0x7fffu + ((u >> 16) & 1u);
    return (unsigned short)(u >> 16);
}
__device__ inline float bflo(unsigned u) { return __uint_as_float(u << 16); }
__device__ inline float bfhi(unsigned u) { return __uint_as_float(u & 0xffff0000u); }

// ---------------------------------------------------------------------------
// init: feat->bf16 (blocks [0,6250)), weight prep (blocks [6250,6646)),
// cursor zero (blocks [6646,7428))
__global__ __launch_bounds__(256) void init_kernel(
    const float* __restrict__ feat, unsigned short* __restrict__ featb,
    const float* __restrict__ W1, const float* __restrict__ b1,
    const float* __restrict__ W2, const float* __restrict__ b2,
    unsigned short* __restrict__ W1T, unsigned short* __restrict__ W2T,
    float* __restrict__ btab1, float* __restrict__ btab2,
    int* __restrict__ dcnt)
{
    int b = blockIdx.x, t = threadIdx.x;
    if (b < 6250) {                          // featb: 6.4M elems, 4/thread
        int i = (b * 256 + t) * 4;
        float4 v = *(const float4*)&feat[i];
        unsigned lo = (unsigned)f2bf(v.x) | ((unsigned)f2bf(v.y) << 16);
        unsigned hi = (unsigned)f2bf(v.z) | ((unsigned)f2bf(v.w) << 16);
        *(uint2*)&featb[i] = make_uint2(lo, hi);
    } else if (b < 6506) {                   // W1T: 65536 elems
        int i = (b - 6250) * 256 + t;
        int j = i >> 9, kc = i & 511, r = kc >> 7, k = kc & 127;
        W1T[i] = f2bf(W1[r * 16384 + k * 128 + j]);
    } else if (b < 6634) {                   // W2T: 32768 elems
        int i = (b - 6506) * 256 + t;
        int j = i >> 9, kc = i & 511, r = kc >> 7, k = kc & 127;
        W2T[i] = f2bf(W2[r * 8192 + k * 64 + j]);
    } else if (b < 6642) {                   // btab1: 2048
        int i = (b - 6634) * 256 + t;
        int mm = i >> 7, c = i & 127;
        float s = 0.f;
        #pragma unroll
        for (int r = 0; r < RR; ++r) if (mm & (1 << r)) s += b1[r * 128 + c];
        btab1[i] = s;
    } else if (b < 6646) {                   // btab2: 1024
        int i = (b - 6642) * 256 + t;
        int mm = i >> 6, c = i & 63;
        float s = 0.f;
        #pragma unroll
        for (int r = 0; r < RR; ++r) if (mm & (1 << r)) s += b2[r * 64 + c];
        btab2[i] = s;
    } else {                                 // dcnt zero: 800000 ints
        int i = ((b - 6646) * 256 + t) * 4;
        if (i < RR * NN * 4) *(int4*)&dcnt[i] = make_int4(0, 0, 0, 0);
    }
}

// ---------------------------------------------------------------------------
// ELL fill: one atomic (16B-strided cursor) + one ushort slot write per edge
__global__ __launch_bounds__(256) void fill_kernel(
    const int* __restrict__ edges, int* __restrict__ dcnt,
    unsigned short* __restrict__ ell)
{
    int e = blockIdx.x * 256 + threadIdx.x;
    int r = blockIdx.y;
    if (e >= EE) return;
    int src = edges[r * 2 * EE + e];
    int dst = edges[r * 2 * EE + EE + e];
    int p = atomicAdd(&dcnt[(r * NN + dst) * 4], 1);
    if (p < SLOTS) ell[((size_t)(r * NN + dst)) * SLOTS + p] = (unsigned short)src;
}

// per-node 4-bit deg>0 mask from cursors
__global__ __launch_bounds__(256) void mask_kernel(
    const int* __restrict__ dcnt, unsigned char* __restrict__ mask)
{
    int v = blockIdx.x * 256 + threadIdx.x;
    if (v >= NN) return;
    unsigned m = 0;
    #pragma unroll
    for (int r = 0; r < RR; ++r)
        if (dcnt[(r * NN + v) * 4] > 0) m |= (1u << r);
    mask[v] = (unsigned char)m;
}

// ---------------------------------------------------------------------------
// segment gather-mean from ELL: quarter-wave (16 lanes x uint4 = 256B row)
// per (node,etype) segment; 4 independent segment streams per wave.
__global__ __launch_bounds__(256) void gather_seg(
    const unsigned short* __restrict__ X,    // [N,128] bf16
    const unsigned short* __restrict__ ell, const int* __restrict__ dcnt,
    unsigned short* __restrict__ agg,        // [MCHUNK,512] bf16
    int base)
{
    int seg = blockIdx.x * 16 + (threadIdx.x >> 4);
    int nl = seg >> 2;
    if (nl >= MCHUNK) return;
    int r    = seg & 3;
    int node = base + nl;
    int l    = threadIdx.x & 15;
    int d = dcnt[(r * NN + node) * 4];
    if (d > SLOTS) d = SLOTS;
    const unsigned short* sp = &ell[((size_t)(r * NN + node)) * SLOTS];
    float a0 = 0.f, a1 = 0.f, a2 = 0.f, a3 = 0.f, a4 = 0.f, a5 = 0.f, a6 = 0.f, a7 = 0.f;
    int j = 0;
    for (; j + 1 < d; j += 2) {
        int s0 = sp[j], s1 = sp[j + 1];
        uint4 u0 = *(const uint4*)&X[(size_t)s0 * 128 + l * 8];
        uint4 u1 = *(const uint4*)&X[(size_t)s1 * 128 + l * 8];
        a0 += bflo(u0.x) + bflo(u1.x); a1 += bfhi(u0.x) + bfhi(u1.x);
        a2 += bflo(u0.y) + bflo(u1.y); a3 += bfhi(u0.y) + bfhi(u1.y);
        a4 += bflo(u0.z) + bflo(u1.z); a5 += bfhi(u0.z) + bfhi(u1.z);
        a6 += bflo(u0.w) + bflo(u1.w); a7 += bfhi(u0.w) + bfhi(u1.w);
    }
    if (j < d) {
        uint4 u0 = *(const uint4*)&X[(size_t)sp[j] * 128 + l * 8];
        a0 += bflo(u0.x); a1 += bfhi(u0.x);
        a2 += bflo(u0.y); a3 += bfhi(u0.y);
        a4 += bflo(u0.z); a5 += bfhi(u0.z);
        a6 += bflo(u0.w); a7 += bfhi(u0.w);
    }
    float inv = (d > 0) ? 1.0f / (float)d : 0.f;
    uint4 o;
    o.x = (unsigned)f2bf(a0 * inv) | ((unsigned)f2bf(a1 * inv) << 16);
    o.y = (unsigned)f2bf(a2 * inv) | ((unsigned)f2bf(a3 * inv) << 16);
    o.z = (unsigned)f2bf(a4 * inv) | ((unsigned)f2bf(a5 * inv) << 16);
    o.w = (unsigned)f2bf(a6 * inv) | ((unsigned)f2bf(a7 * inv) << 16);
    *(uint4*)&agg[(size_t)nl * 512 + r * 128 + l * 8] = o;
}

// ---------------------------------------------------------------------------
// concat GEMM: C[MCHUNK x ON] = A[MCHUNK x 512]_bf16 @ WT^T + btab[mask]
template<int ON, bool RELU_BF16>
__global__ __launch_bounds__(256) void gemm_cat(
    const unsigned short* __restrict__ A, const unsigned short* __restrict__ WT,
    const float* __restrict__ btab, const unsigned char* __restrict__ mask,
    void* __restrict__ Cout, int base)
{
    constexpr int NT = ON / 16;
    __shared__ __align__(16) unsigned short Al[64 * LDA];
    __shared__ __align__(16) unsigned short Wl[ON * LDA];
    const int tid  = threadIdx.x;
    const int wv   = tid >> 6;
    const int lane = tid & 63;
    const int m    = lane & 15;
    const int q    = lane >> 4;
    const int row0 = blockIdx.x * 64;

    f32x4 acc[NT];
    #pragma unroll
    for (int nt = 0; nt < NT; ++nt) acc[nt] = (f32x4){0.f, 0.f, 0.f, 0.f};

    for (int ks = 0; ks < 4; ++ks) {
        #pragma unroll
        for (int it = 0; it < 4; ++it) {
            int i = it * 256 + tid;
            int rr = i >> 4, ko = i & 15;
            int row = row0 + rr;
            uint4 v = make_uint4(0, 0, 0, 0);
            if (row < MCHUNK) v = *(const uint4*)&A[(size_t)row * 512 + ks * 128 + ko * 8];
            *(uint4*)&Al[rr * LDA + ko * 8] = v;
        }
        for (int i = tid; i < ON * 16; i += 256) {
            int nr = i >> 4, ko = i & 15;
            *(uint4*)&Wl[nr * LDA + ko * 8] =
                *(const uint4*)&WT[(size_t)nr * 512 + ks * 128 + ko * 8];
        }
        __syncthreads();

        bf16x8 afr[4];
        #pragma unroll
        for (int kq = 0; kq < 4; ++kq)
            afr[kq] = *(const bf16x8*)&Al[(wv * 16 + m) * LDA + kq * 32 + q * 8];
        #pragma unroll
        for (int nt = 0; nt < NT; ++nt) {
            #pragma unroll
            for (int kq = 0; kq < 4; ++kq) {
                bf16x8 bfr = *(const bf16x8*)&Wl[(nt * 16 + m) * LDA + kq * 32 + q * 8];
                acc[nt] = __builtin_amdgcn_mfma_f32_16x16x32_bf16(afr[kq], bfr, acc[nt], 0, 0, 0);
            }
        }
        __syncthreads();
    }

    int rloc[4]; int mk[4];
    #pragma unroll
    for (int rg = 0; rg < 4; ++rg) {
        rloc[rg] = row0 + wv * 16 + q * 4 + rg;
        mk[rg] = (rloc[rg] < MCHUNK) ? (int)mask[base + rloc[rg]] : 0;
    }
    #pragma unroll
    for (int nt = 0; nt < NT; ++nt) {
        int col = nt * 16 + m;
        #pragma unroll
        for (int rg = 0; rg < 4; ++rg) {
            if (rloc[rg] < MCHUNK) {
                size_t gnode = (size_t)(base + rloc[rg]);
                float val = acc[nt][rg] + btab[mk[rg] * ON + col];
                if (RELU_BF16)
                    ((unsigned short*)Cout)[gnode * ON + col] = f2bf(fmaxf(val, 0.f));
                else
                    ((float*)Cout)[gnode * ON + col] = val;
            }
        }
    }
}

// ---------------------------------------------------------------------------
extern "C" void kernel_launch(void* const* d_in, const int* in_sizes, int n_in,
                              void* d_out, int out_size, void* d_ws, size_t ws_size,
                              hipStream_t stream)
{
    const float* feat  = (const float*)d_in[0];   // [N,128]
    const float* W1    = (const float*)d_in[1];   // [R,128,128]
    const float* b1    = (const float*)d_in[2];   // [R,128]
    const float* W2    = (const float*)d_in[3];   // [R,128,64]
    const float* b2    = (const float*)d_in[4];   // [R,64]
    const int*   edges = (const int*)d_in[5];     // [R,2,E]
    float* out = (float*)d_out;                   // [N,64] fp32

    // workspace (~54.8 MB)
    char* p = (char*)d_ws;
    auto alloc = [&](size_t bytes) { char* q = p; p += (bytes + 255) & ~(size_t)255; return q; };
    int* dcnt              = (int*)alloc((size_t)RR * NN * 4 * 4);            // padded x4: 3.2MB
    unsigned short* ell    = (unsigned short*)alloc((size_t)RR * NN * SLOTS * 2); // 12.8MB
    unsigned char* mask    = (unsigned char*)alloc(NN + 64);
    unsigned short* W1T    = (unsigned short*)alloc((size_t)128 * 512 * 2);
    unsigned short* W2T    = (unsigned short*)alloc((size_t)64 * 512 * 2);
    float* btab1           = (float*)alloc((size_t)16 * 128 * 4);
    float* btab2           = (float*)alloc((size_t)16 * 64 * 4);
    unsigned short* featb  = (unsigned short*)alloc((size_t)NN * 128 * 2);    // 12.8MB
    unsigned short* h1r    = (unsigned short*)alloc((size_t)NN * 128 * 2);    // 12.8MB
    unsigned short* agg    = (unsigned short*)alloc((size_t)MCHUNK * 512 * 2);// 12.8MB

    // init: featb + weight prep + cursor zero (one kernel)
    init_kernel<<<7428, 256, 0, stream>>>(feat, featb, W1, b1, W2, b2,
                                          W1T, W2T, btab1, btab2, dcnt);
    // ELL build
    dim3 eg((EE + 255) / 256, RR);
    fill_kernel<<<eg, 256, 0, stream>>>(edges, dcnt, ell);
    mask_kernel<<<(NN + 255) / 256, 256, 0, stream>>>(dcnt, mask);

    const int SEGB = MCHUNK * 4 / 16;          // 3125
    const int GG   = (MCHUNK + 63) / 64;       // 196

    // layer 1: gather(featb) -> agg -> concat GEMM + relu -> h1r (bf16)
    for (int c = 0; c < 4; ++c) {
        int base = c * MCHUNK;
        gather_seg<<<SEGB, 256, 0, stream>>>(featb, ell, dcnt, agg, base);
        gemm_cat<128, true><<<GG, 256, 0, stream>>>(agg, W1T, btab1, mask, h1r, base);
    }
    // layer 2: gather(h1r) -> agg -> concat GEMM -> out (fp32)
    for (int c = 0; c < 4; ++c) {
        int base = c * MCHUNK;
        gather_seg<<<SEGB, 256, 0, stream>>>(h1r, ell, dcnt, agg, base);
        gemm_cat<64, false><<<GG, 256, 0, stream>>>(agg, W2T, btab2, mask, out, base);
    }
}

// Round 8
// 324.793 us; speedup vs baseline: 1.1512x; 1.1512x over previous
//
#include <hip/hip_runtime.h>

#define NN 50000
#define EE 200000
#define RR 4
#define MCHUNK 25000

#define SC_TOTAL (RR * NN)                                   // 200000
#define SC_BLOCKS ((SC_TOTAL + 1023) / 1024)                 // 196

#define LDA 136   // LDS row stride (ushorts): 16B-aligned rows, frag reads <=2-way conflict (free)

typedef __attribute__((ext_vector_type(8))) short bf16x8;
typedef __attribute__((ext_vector_type(4))) float f32x4;

__device__ inline unsigned short f2bf(float x) {   // round-to-nearest-even
    unsigned int u = __float_as_uint(x);
    u += 0x7fffu + ((u >> 16) & 1u);
    return (unsigned short)(u >> 16);
}
__device__ inline float bflo(unsigned u) { return __uint_as_float(u << 16); }
__device__ inline float bfhi(unsigned u) { return __uint_as_float(u & 0xffff0000u); }

// ---------------------------------------------------------------------------
// init: featb (blocks [0,6250)), W1T [6250,6506), W2T [6506,6634),
// btab1 [6634,6642), btab2 [6642,6646), counts zero [6646,6842)
__global__ __launch_bounds__(256) void init_kernel(
    const float* __restrict__ feat, unsigned short* __restrict__ featb,
    const float* __restrict__ W1, const float* __restrict__ b1,
    const float* __restrict__ W2, const float* __restrict__ b2,
    unsigned short* __restrict__ W1T, unsigned short* __restrict__ W2T,
    float* __restrict__ btab1, float* __restrict__ btab2,
    int* __restrict__ counts)
{
    int b = blockIdx.x, t = threadIdx.x;
    if (b < 6250) {                          // featb: 6.4M elems, 4/thread
        int i = (b * 256 + t) * 4;
        float4 v = *(const float4*)&feat[i];
        unsigned lo = (unsigned)f2bf(v.x) | ((unsigned)f2bf(v.y) << 16);
        unsigned hi = (unsigned)f2bf(v.z) | ((unsigned)f2bf(v.w) << 16);
        *(uint2*)&featb[i] = make_uint2(lo, hi);
    } else if (b < 6506) {                   // W1T: 65536 elems
        int i = (b - 6250) * 256 + t;
        int j = i >> 9, kc = i & 511, r = kc >> 7, k = kc & 127;
        W1T[i] = f2bf(W1[r * 16384 + k * 128 + j]);
    } else if (b < 6634) {                   // W2T: 32768 elems
        int i = (b - 6506) * 256 + t;
        int j = i >> 9, kc = i & 511, r = kc >> 7, k = kc & 127;
        W2T[i] = f2bf(W2[r * 8192 + k * 64 + j]);
    } else if (b < 6642) {                   // btab1: 2048
        int i = (b - 6634) * 256 + t;
        int mm = i >> 7, c = i & 127;
        float s = 0.f;
        #pragma unroll
        for (int r = 0; r < RR; ++r) if (mm & (1 << r)) s += b1[r * 128 + c];
        btab1[i] = s;
    } else if (b < 6646) {                   // btab2: 1024
        int i = (b - 6642) * 256 + t;
        int mm = i >> 6, c = i & 63;
        float s = 0.f;
        #pragma unroll
        for (int r = 0; r < RR; ++r) if (mm & (1 << r)) s += b2[r * 64 + c];
        btab2[i] = s;
    } else {                                 // counts zero: 200000 ints
        int i = ((b - 6646) * 256 + t) * 4;
        if (i < SC_TOTAL) *(int4*)&counts[i] = make_int4(0, 0, 0, 0);
    }
}

// ---------------------------------------------------------------------------
// hist: 4 edges/thread (MLP=4), fire-and-forget atomics
__global__ __launch_bounds__(256) void hist_kernel(
    const int* __restrict__ edges, int* __restrict__ counts)
{
    int r = blockIdx.y;
    int e0 = blockIdx.x * 1024 + threadIdx.x;
    const int* ed = edges + (size_t)r * 2 * EE + EE;
    int d[4];
    #pragma unroll
    for (int k = 0; k < 4; ++k) {
        int e = e0 + k * 256;
        d[k] = (e < EE) ? ed[e] : -1;
    }
    #pragma unroll
    for (int k = 0; k < 4; ++k)
        if (d[k] >= 0) atomicAdd(&counts[r * NN + d[k]], 1);
}

__global__ __launch_bounds__(256) void scan_p1(
    const int* __restrict__ c, int* __restrict__ bsum)
{
    __shared__ int l[256];
    int t = threadIdx.x;
    int idx = (blockIdx.x * 256 + t) * 4;
    int s = 0;
    if (idx + 3 < SC_TOTAL) { int4 v = *(const int4*)&c[idx]; s = v.x + v.y + v.z + v.w; }
    else { for (int i = idx; i < SC_TOTAL; ++i) s += c[i]; }
    l[t] = s; __syncthreads();
    for (int off = 128; off > 0; off >>= 1) {
        if (t < off) l[t] += l[t + off];
        __syncthreads();
    }
    if (t == 0) bsum[blockIdx.x] = l[0];
}

__global__ __launch_bounds__(256) void scan_p2(
    int* __restrict__ bsum, int* __restrict__ offsets)
{
    __shared__ int l[256];
    int t = threadIdx.x;
    int v = (t < SC_BLOCKS) ? bsum[t] : 0;
    l[t] = v; __syncthreads();
    for (int off = 1; off < 256; off <<= 1) {
        int x = (t >= off) ? l[t - off] : 0;
        __syncthreads();
        l[t] += x;
        __syncthreads();
    }
    if (t < SC_BLOCKS) bsum[t] = (t > 0) ? l[t - 1] : 0;
    if (t == 0) offsets[SC_TOTAL] = RR * EE;   // sentinel
}

// phase 3: offsets + cursor copy. cur ALIASES counts (private read-then-write, safe)
__global__ __launch_bounds__(256) void scan_p3(
    const int* __restrict__ c, const int* __restrict__ bsum,
    int* __restrict__ offsets, int* __restrict__ cur)
{
    __shared__ int l[256];
    int t = threadIdx.x;
    int idx = (blockIdx.x * 256 + t) * 4;
    int e0 = 0, e1 = 0, e2 = 0, e3 = 0;
    if (idx + 3 < SC_TOTAL) { int4 v = *(const int4*)&c[idx]; e0 = v.x; e1 = v.y; e2 = v.z; e3 = v.w; }
    else {
        if (idx     < SC_TOTAL) e0 = c[idx];
        if (idx + 1 < SC_TOTAL) e1 = c[idx + 1];
        if (idx + 2 < SC_TOTAL) e2 = c[idx + 2];
        if (idx + 3 < SC_TOTAL) e3 = c[idx + 3];
    }
    int s = e0 + e1 + e2 + e3;
    l[t] = s; __syncthreads();
    for (int off = 1; off < 256; off <<= 1) {
        int x = (t >= off) ? l[t - off] : 0;
        __syncthreads();
        l[t] += x;
        __syncthreads();
    }
    int base = bsum[blockIdx.x] + ((t > 0) ? l[t - 1] : 0);
    int o0 = base, o1 = base + e0, o2 = base + e0 + e1, o3 = base + e0 + e1 + e2;
    if (idx     < SC_TOTAL) { offsets[idx]     = o0; cur[idx]     = o0; }
    if (idx + 1 < SC_TOTAL) { offsets[idx + 1] = o1; cur[idx + 1] = o1; }
    if (idx + 2 < SC_TOTAL) { offsets[idx + 2] = o2; cur[idx + 2] = o2; }
    if (idx + 3 < SC_TOTAL) { offsets[idx + 3] = o3; cur[idx + 3] = o3; }
}

// fill: 4 edges/thread (MLP=4 on the atomic round-trip), ushort ssrc
__global__ __launch_bounds__(256) void fill_kernel(
    const int* __restrict__ edges, int* __restrict__ cur,
    unsigned short* __restrict__ ssrc)
{
    int r = blockIdx.y;
    int e0 = blockIdx.x * 1024 + threadIdx.x;
    const int* es = edges + (size_t)r * 2 * EE;
    int src[4], dst[4], p[4];
    #pragma unroll
    for (int k = 0; k < 4; ++k) {
        int e = e0 + k * 256;
        src[k] = (e < EE) ? es[e] : 0;
        dst[k] = (e < EE) ? es[EE + e] : -1;
    }
    #pragma unroll
    for (int k = 0; k < 4; ++k)
        if (dst[k] >= 0) p[k] = atomicAdd(&cur[r * NN + dst[k]], 1);
    #pragma unroll
    for (int k = 0; k < 4; ++k)
        if (dst[k] >= 0) ssrc[p[k]] = (unsigned short)src[k];
}

// per-node 4-bit deg>0 mask
__global__ __launch_bounds__(256) void mask_kernel(
    const int* __restrict__ off, unsigned char* __restrict__ mask)
{
    int v = blockIdx.x * 256 + threadIdx.x;
    if (v >= NN) return;
    unsigned m = 0;
    #pragma unroll
    for (int r = 0; r < RR; ++r)
        if (off[r * NN + v + 1] > off[r * NN + v]) m |= (1u << r);
    mask[v] = (unsigned char)m;
}

// ---------------------------------------------------------------------------
// segment gather-mean: quarter-wave (16 lanes x uint4 = 256B row) per
// (node,etype) segment; 4 independent segment streams per wave.
__global__ __launch_bounds__(256) void gather_seg(
    const unsigned short* __restrict__ X,   // [N,128] bf16
    const unsigned short* __restrict__ ssrc, const int* __restrict__ off,
    unsigned short* __restrict__ agg,       // [MCHUNK,512] bf16
    int base)
{
    int seg = blockIdx.x * 16 + (threadIdx.x >> 4);
    int nl = seg >> 2;
    if (nl >= MCHUNK) return;
    int r    = seg & 3;
    int node = base + nl;
    int l    = threadIdx.x & 15;
    int s = off[r * NN + node];
    int e = off[r * NN + node + 1];
    float a0 = 0.f, a1 = 0.f, a2 = 0.f, a3 = 0.f, a4 = 0.f, a5 = 0.f, a6 = 0.f, a7 = 0.f;
    int j = s;
    for (; j + 1 < e; j += 2) {
        int s0 = ssrc[j], s1 = ssrc[j + 1];
        uint4 u0 = *(const uint4*)&X[(size_t)s0 * 128 + l * 8];
        uint4 u1 = *(const uint4*)&X[(size_t)s1 * 128 + l * 8];
        a0 += bflo(u0.x) + bflo(u1.x); a1 += bfhi(u0.x) + bfhi(u1.x);
        a2 += bflo(u0.y) + bflo(u1.y); a3 += bfhi(u0.y) + bfhi(u1.y);
        a4 += bflo(u0.z) + bflo(u1.z); a5 += bfhi(u0.z) + bfhi(u1.z);
        a6 += bflo(u0.w) + bflo(u1.w); a7 += bfhi(u0.w) + bfhi(u1.w);
    }
    if (j < e) {
        uint4 u0 = *(const uint4*)&X[(size_t)ssrc[j] * 128 + l * 8];
        a0 += bflo(u0.x); a1 += bfhi(u0.x);
        a2 += bflo(u0.y); a3 += bfhi(u0.y);
        a4 += bflo(u0.z); a5 += bfhi(u0.z);
        a6 += bflo(u0.w); a7 += bfhi(u0.w);
    }
    float inv = (e > s) ? 1.0f / (float)(e - s) : 0.f;
    uint4 o;
    o.x = (unsigned)f2bf(a0 * inv) | ((unsigned)f2bf(a1 * inv) << 16);
    o.y = (unsigned)f2bf(a2 * inv) | ((unsigned)f2bf(a3 * inv) << 16);
    o.z = (unsigned)f2bf(a4 * inv) | ((unsigned)f2bf(a5 * inv) << 16);
    o.w = (unsigned)f2bf(a6 * inv) | ((unsigned)f2bf(a7 * inv) << 16);
    *(uint4*)&agg[(size_t)nl * 512 + r * 128 + l * 8] = o;
}

// ---------------------------------------------------------------------------
// concat GEMM: C[MCHUNK x ON] = A[MCHUNK x 512]_bf16 @ WT^T + btab[mask]
template<int ON, bool RELU_BF16>
__global__ __launch_bounds__(256) void gemm_cat(
    const unsigned short* __restrict__ A, const unsigned short* __restrict__ WT,
    const float* __restrict__ btab, const unsigned char* __restrict__ mask,
    void* __restrict__ Cout, int base)
{
    constexpr int NT = ON / 16;
    __shared__ __align__(16) unsigned short Al[64 * LDA];
    __shared__ __align__(16) unsigned short Wl[ON * LDA];
    const int tid  = threadIdx.x;
    const int wv   = tid >> 6;
    const int lane = tid & 63;
    const int m    = lane & 15;
    const int q    = lane >> 4;
    const int row0 = blockIdx.x * 64;

    f32x4 acc[NT];
    #pragma unroll
    for (int nt = 0; nt < NT; ++nt) acc[nt] = (f32x4){0.f, 0.f, 0.f, 0.f};

    for (int ks = 0; ks < 4; ++ks) {
        #pragma unroll
        for (int it = 0; it < 4; ++it) {
            int i = it * 256 + tid;
            int rr = i >> 4, ko = i & 15;
            int row = row0 + rr;
            uint4 v = make_uint4(0, 0, 0, 0);
            if (row < MCHUNK) v = *(const uint4*)&A[(size_t)row * 512 + ks * 128 + ko * 8];
            *(uint4*)&Al[rr * LDA + ko * 8] = v;
        }
        for (int i = tid; i < ON * 16; i += 256) {
            int nr = i >> 4, ko = i & 15;
            *(uint4*)&Wl[nr * LDA + ko * 8] =
                *(const uint4*)&WT[(size_t)nr * 512 + ks * 128 + ko * 8];
        }
        __syncthreads();

        bf16x8 afr[4];
        #pragma unroll
        for (int kq = 0; kq < 4; ++kq)
            afr[kq] = *(const bf16x8*)&Al[(wv * 16 + m) * LDA + kq * 32 + q * 8];
        #pragma unroll
        for (int nt = 0; nt < NT; ++nt) {
            #pragma unroll
            for (int kq = 0; kq < 4; ++kq) {
                bf16x8 bfr = *(const bf16x8*)&Wl[(nt * 16 + m) * LDA + kq * 32 + q * 8];
                acc[nt] = __builtin_amdgcn_mfma_f32_16x16x32_bf16(afr[kq], bfr, acc[nt], 0, 0, 0);
            }
        }
        __syncthreads();
    }

    int rloc[4]; int mk[4];
    #pragma unroll
    for (int rg = 0; rg < 4; ++rg) {
        rloc[rg] = row0 + wv * 16 + q * 4 + rg;
        mk[rg] = (rloc[rg] < MCHUNK) ? (int)mask[base + rloc[rg]] : 0;
    }
    #pragma unroll
    for (int nt = 0; nt < NT; ++nt) {
        int col = nt * 16 + m;
        #pragma unroll
        for (int rg = 0; rg < 4; ++rg) {
            if (rloc[rg] < MCHUNK) {
                size_t gnode = (size_t)(base + rloc[rg]);
                float val = acc[nt][rg] + btab[mk[rg] * ON + col];
                if (RELU_BF16)
                    ((unsigned short*)Cout)[gnode * ON + col] = f2bf(fmaxf(val, 0.f));
                else
                    ((float*)Cout)[gnode * ON + col] = val;
            }
        }
    }
}

// ---------------------------------------------------------------------------
extern "C" void kernel_launch(void* const* d_in, const int* in_sizes, int n_in,
                              void* d_out, int out_size, void* d_ws, size_t ws_size,
                              hipStream_t stream)
{
    const float* feat  = (const float*)d_in[0];   // [N,128]
    const float* W1    = (const float*)d_in[1];   // [R,128,128]
    const float* b1    = (const float*)d_in[2];   // [R,128]
    const float* W2    = (const float*)d_in[3];   // [R,128,64]
    const float* b2    = (const float*)d_in[4];   // [R,64]
    const int*   edges = (const int*)d_in[5];     // [R,2,E]
    float* out = (float*)d_out;                   // [N,64] fp32

    // workspace (~54.6 MB; cur aliases counts)
    char* p = (char*)d_ws;
    auto alloc = [&](size_t bytes) { char* q = p; p += (bytes + 255) & ~(size_t)255; return q; };
    int* counts            = (int*)alloc((size_t)SC_TOTAL * 4);
    int* offsets           = (int*)alloc((size_t)(SC_TOTAL + 4) * 4);
    int* bsum              = (int*)alloc(1024);
    unsigned short* ssrc   = (unsigned short*)alloc((size_t)RR * EE * 2);
    unsigned char* mask    = (unsigned char*)alloc(NN + 64);
    unsigned short* W1T    = (unsigned short*)alloc((size_t)128 * 512 * 2);
    unsigned short* W2T    = (unsigned short*)alloc((size_t)64 * 512 * 2);
    float* btab1           = (float*)alloc((size_t)16 * 128 * 4);
    float* btab2           = (float*)alloc((size_t)16 * 64 * 4);
    unsigned short* featb  = (unsigned short*)alloc((size_t)NN * 128 * 2);    // 12.8MB
    unsigned short* h1r    = (unsigned short*)alloc((size_t)NN * 128 * 2);    // 12.8MB
    unsigned short* agg    = (unsigned short*)alloc((size_t)MCHUNK * 512 * 2);// 25.6MB
    int* cur = counts;   // alias: counts dead after scan_p3 reads them

    init_kernel<<<6842, 256, 0, stream>>>(feat, featb, W1, b1, W2, b2,
                                          W1T, W2T, btab1, btab2, counts);

    // CSR build (shared by both layers)
    dim3 eg((EE + 1023) / 1024, RR);   // 4 edges/thread
    hist_kernel<<<eg, 256, 0, stream>>>(edges, counts);
    scan_p1<<<SC_BLOCKS, 256, 0, stream>>>(counts, bsum);
    scan_p2<<<1, 256, 0, stream>>>(bsum, offsets);
    scan_p3<<<SC_BLOCKS, 256, 0, stream>>>(counts, bsum, offsets, cur);
    fill_kernel<<<eg, 256, 0, stream>>>(edges, cur, ssrc);
    mask_kernel<<<(NN + 255) / 256, 256, 0, stream>>>(offsets, mask);

    const int SEGB = MCHUNK * 4 / 16;          // 6250
    const int GG   = (MCHUNK + 63) / 64;       // 391

    // layer 1: gather(featb) -> agg -> concat GEMM + relu -> h1r (bf16)
    for (int c = 0; c < 2; ++c) {
        int base = c * MCHUNK;
        gather_seg<<<SEGB, 256, 0, stream>>>(featb, ssrc, offsets, agg, base);
        gemm_cat<128, true><<<GG, 256, 0, stream>>>(agg, W1T, btab1, mask, h1r, base);
    }
    // layer 2: gather(h1r) -> agg -> concat GEMM -> out (fp32)
    for (int c = 0; c < 2; ++c) {
        int base = c * MCHUNK;
        gather_seg<<<SEGB, 256, 0, stream>>>(h1r, ssrc, offsets, agg, base);
        gemm_cat<64, false><<<GG, 256, 0, stream>>>(agg, W2T, btab2, mask, out, base);
    }
}